// Round 1
// baseline (11227.478 us; speedup 1.0000x reference)
//
#include <hip/hip_runtime.h>

// VaeRNNDecoder: 512-step LSTM with output feedback, B=256, H=512.
// Folded recurrence: gates_t = h_t @ W_eff^T + b_eff,  W_eff = W_ih@W_last + W_hh.
// 8 groups (XCD-affine) x 32 slice-blocks; weights persistent in VGPRs as fp16
// MFMA B-fragments; per-step h exchange via LLC + agent-scope group barrier.

#define HH 512
#define TT 512

typedef _Float16 half8 __attribute__((ext_vector_type(8)));
typedef float f32x4 __attribute__((ext_vector_type(4)));

__device__ __forceinline__ float sigm(float x) { return 1.0f / (1.0f + __expf(-x)); }
__device__ __forceinline__ float tanh_(float x) { return 1.0f - 2.0f / (__expf(2.0f * x) + 1.0f); }
__device__ __forceinline__ unsigned short f16b(float x) {
    _Float16 h = (_Float16)x;
    return __builtin_bit_cast(unsigned short, h);
}

// ---------------- K1: W_eff gate rows -> Wbig (packed, f16) ----------------
// E = W_ih @ W_last + W_hh   (2048x512). Row gr -> Wbig row 80*(j>>4) + q*16 + (j&15),
// with q = gr>>9 (gate i,f,g,o), j = gr&511.
__global__ __launch_bounds__(256) void k_weff(const float* __restrict__ Wih,
                                              const float* __restrict__ Whh,
                                              const float* __restrict__ Wlast,
                                              unsigned short* __restrict__ Wbig) {
    __shared__ float wih[16 * 512];
    const int tid = threadIdx.x;
    const int r0 = blockIdx.x * 16;
    for (int i = tid; i < (16 * 512) / 4; i += 256) {
        ((float4*)wih)[i] = ((const float4*)(Wih + (size_t)r0 * 512))[i];
    }
    __syncthreads();
    float acc0[16], acc1[16];
#pragma unroll
    for (int rr = 0; rr < 16; ++rr) { acc0[rr] = 0.f; acc1[rr] = 0.f; }
    const int k0 = tid * 2;
    for (int j = 0; j < 512; ++j) {
        const float2 wl = *(const float2*)(Wlast + (size_t)j * 512 + k0);
#pragma unroll
        for (int rr = 0; rr < 16; ++rr) {
            const float a = wih[rr * 512 + j];
            acc0[rr] += a * wl.x;
            acc1[rr] += a * wl.y;
        }
    }
#pragma unroll
    for (int rr = 0; rr < 16; ++rr) {
        const int gr = r0 + rr;
        const int q = gr >> 9, j = gr & 511;
        const int dst = 80 * (j >> 4) + q * 16 + (j & 15);
        const float v0 = acc0[rr] + Whh[(size_t)gr * 512 + k0];
        const float v1 = acc1[rr] + Whh[(size_t)gr * 512 + k0 + 1];
        Wbig[(size_t)dst * 512 + k0] = f16b(v0);
        Wbig[(size_t)dst * 512 + k0 + 1] = f16b(v1);
    }
}

// ---------------- K2: pack W0big, y-rows, biases, hbuf init, counters ------
__global__ __launch_bounds__(256) void k_pack(const float* __restrict__ z,
                                              const float* __restrict__ Wih,
                                              const float* __restrict__ Whh,
                                              const float* __restrict__ bih,
                                              const float* __restrict__ bhh,
                                              const float* __restrict__ Wlast,
                                              const float* __restrict__ blast,
                                              unsigned short* __restrict__ Wbig,
                                              unsigned short* __restrict__ W0big,
                                              float* __restrict__ biasEff,
                                              float* __restrict__ bias0,
                                              unsigned short* __restrict__ hbuf,
                                              unsigned int* __restrict__ counters) {
    const int nthr = gridDim.x * blockDim.x;
    const int gtid = blockIdx.x * blockDim.x + threadIdx.x;
    // A: W0big gate rows = f16(Wih+Whh); y rows (tau==4) = f16(Wlast) into both.
    for (int e = gtid; e < 2560 * 512; e += nthr) {
        const int r = e >> 9, k = e & 511;
        const int s = r / 80, rem = r - s * 80;
        const int tau = rem >> 4, jj = rem & 15;
        const int j = s * 16 + jj;
        if (tau == 4) {
            const unsigned short v = f16b(Wlast[(size_t)j * 512 + k]);
            Wbig[e] = v;
            W0big[e] = v;
        } else {
            const int gr = tau * 512 + j;
            W0big[e] = f16b(Wih[(size_t)gr * 512 + k] + Whh[(size_t)gr * 512 + k]);
        }
    }
    // B: biases. bias_eff gate rows = b_ih+b_hh + W_ih@b_last; y rows = b_last.
    for (int r = gtid; r < 2560; r += nthr) {
        const int s = r / 80, rem = r - s * 80;
        const int tau = rem >> 4, jj = rem & 15;
        const int j = s * 16 + jj;
        if (tau == 4) {
            bias0[r] = blast[j];
            biasEff[r] = blast[j];
        } else {
            const int gr = tau * 512 + j;
            const float base = bih[gr] + bhh[gr];
            float dot = 0.f;
            for (int k = 0; k < 512; ++k) dot += Wih[(size_t)gr * 512 + k] * blast[k];
            bias0[r] = base;
            biasEff[r] = base + dot;
        }
    }
    // C: hbuf parity 0 = f16(z), grouped by batch: group g owns b = g*32..g*32+31.
    for (int e = gtid; e < 256 * 512; e += nthr) {
        const int b = e >> 9, k = e & 511;
        const int g = b >> 5, bl = b & 31;
        hbuf[((size_t)(g * 2) * 32 + bl) * 512 + k] = f16b(z[e]);
    }
    // D: barrier counters.
    for (int e = gtid; e < 512; e += nthr) counters[e] = 0u;
}

// ---------------- K3: persistent recurrence ----------------
// 256 blocks = 8 groups (blockIdx&7, XCD-affine) x 32 slices (blockIdx>>3).
// Block owns 16 hidden indices j in [16s,16s+16): 64 gate rows + 16 y rows.
// Waves: w0: Mtile0 x {i,f,g}; w1: Mtile0 x {o,y}; w2: Mtile1 x {i,f,g}; w3: Mtile1 x {o,y}.
__global__ __launch_bounds__(256, 1) void k_lstm(const unsigned short* __restrict__ Wbig,
                                                 const unsigned short* __restrict__ W0big,
                                                 const float* __restrict__ biasEff,
                                                 const float* __restrict__ bias0,
                                                 unsigned short* __restrict__ hbuf,
                                                 unsigned int* __restrict__ counters,
                                                 const float* __restrict__ z,
                                                 float* __restrict__ out) {
    const int g = blockIdx.x & 7;
    const int s = blockIdx.x >> 3;
    const int tid = threadIdx.x;
    const int wave = tid >> 6;
    const int lane = tid & 63;
    const int l15 = lane & 15;
    const int q4 = lane >> 4;

    __shared__ unsigned short hstage[32 * 520];  // padded rows: stride 520 halves
    __shared__ float gatesL[32 * 64];            // [b][i(16) f(16) g(16) o(16)]
    __shared__ float cL[32 * 16];                // cell state, block-local

    const int mbase = (wave >> 1) * 16;
    const int ntile0 = (wave & 1) ? 3 : 0;
    const int ntcount = (wave & 1) ? 2 : 3;

    unsigned short* hb0 = hbuf + (size_t)(g * 2) * 32 * 512;
    unsigned short* hb1 = hb0 + 32 * 512;
    unsigned int* cnt = counters + g * 64;

    // c init from z (fp32 exact)
    for (int idx = tid; idx < 512; idx += 256) {
        const int b = idx >> 4, jj = idx & 15;
        cL[b * 16 + jj] = z[(size_t)(g * 32 + b) * 512 + 16 * s + jj];
    }

    // persistent B-fragments (fp16 weights in VGPRs), start with W0
    half8 bfrag[3][16];
#pragma unroll
    for (int tt = 0; tt < 3; ++tt) {
        if (tt < ntcount) {
            const int row = 80 * s + (ntile0 + tt) * 16 + l15;
#pragma unroll
            for (int kk = 0; kk < 16; ++kk) {
                bfrag[tt][kk] = *(const half8*)(W0big + (size_t)row * 512 + kk * 32 + q4 * 8);
            }
        }
    }
    float bias0v[3], biasEv[3];
#pragma unroll
    for (int tt = 0; tt < 3; ++tt) {
        if (tt < ntcount) {
            const int r = 80 * s + (ntile0 + tt) * 16 + l15;
            bias0v[tt] = bias0[r];
            biasEv[tt] = biasEff[r];
        } else {
            bias0v[tt] = 0.f;
            biasEv[tt] = 0.f;
        }
    }

    for (int t = 0; t <= 512; ++t) {
        // ---- stage h(t) from global exchange buffer into padded LDS ----
        const unsigned short* src = (t & 1) ? hb1 : hb0;
#pragma unroll
        for (int i = 0; i < 8; ++i) {
            const int ci = i * 256 + tid;  // 16B chunk index, 0..2047
            const int row = ci >> 6, col = ci & 63;
            *(half8*)(hstage + row * 520 + col * 8) = *(const half8*)(src + ci * 8);
        }
        __syncthreads();

        // ---- MFMA: [gates | y] = h @ Wbig_slice^T + bias ----
        f32x4 acc[3];
#pragma unroll
        for (int tt = 0; tt < 3; ++tt) {
            const float bv = (t == 0) ? bias0v[tt] : biasEv[tt];
            acc[tt] = (f32x4){bv, bv, bv, bv};
        }
#pragma unroll
        for (int kk = 0; kk < 16; ++kk) {
            const half8 a = *(const half8*)(hstage + (mbase + l15) * 520 + kk * 32 + q4 * 8);
#pragma unroll
            for (int tt = 0; tt < 3; ++tt) {
                if (tt < ntcount)
                    acc[tt] = __builtin_amdgcn_mfma_f32_16x16x32_f16(a, bfrag[tt][kk], acc[tt], 0, 0, 0);
            }
        }

        // ---- y_{t-1} output (waves 1/3 hold the y tile in acc[1]) ----
        if ((wave & 1) && t >= 1) {
            const int n = 16 * s + l15;
#pragma unroll
            for (int r = 0; r < 4; ++r) {
                const int m = mbase + q4 * 4 + r;
                const size_t off = (size_t)(g * 32 + m) * (TT * HH) + (size_t)(t - 1) * HH + n;
                __builtin_nontemporal_store(acc[1][r], out + off);
            }
        }
        if (t == 512) break;

        // ---- gate tiles -> LDS ----
        {
            const int nst = (wave & 1) ? 1 : 3;
#pragma unroll
            for (int tt = 0; tt < 3; ++tt) {
                if (tt < nst) {
                    const int col = (ntile0 + tt) * 16 + l15;
#pragma unroll
                    for (int r = 0; r < 4; ++r) {
                        const int m = mbase + q4 * 4 + r;
                        gatesL[m * 64 + col] = acc[tt][r];
                    }
                }
            }
        }
        __syncthreads();

        // ---- cell update: 2 cells per thread; publish h(t+1) write-through ----
        {
            const int b = tid >> 3, jp = tid & 7;
            const int j0 = jp * 2;
            const float2 iv = *(const float2*)(gatesL + b * 64 + j0);
            const float2 fv = *(const float2*)(gatesL + b * 64 + 16 + j0);
            const float2 gv = *(const float2*)(gatesL + b * 64 + 32 + j0);
            const float2 ov = *(const float2*)(gatesL + b * 64 + 48 + j0);
            float2 cv = *(const float2*)(cL + b * 16 + j0);
            const float c0 = sigm(fv.x) * cv.x + sigm(iv.x) * tanh_(gv.x);
            const float c1 = sigm(fv.y) * cv.y + sigm(iv.y) * tanh_(gv.y);
            const float h0 = sigm(ov.x) * tanh_(c0);
            const float h1 = sigm(ov.y) * tanh_(c1);
            cv.x = c0;
            cv.y = c1;
            *(float2*)(cL + b * 16 + j0) = cv;
            unsigned short* dst = (t & 1) ? hb0 : hb1;  // parity (t+1)&1
            const unsigned int packed = (unsigned int)f16b(h0) | ((unsigned int)f16b(h1) << 16);
            __hip_atomic_store((unsigned int*)(dst + b * 512 + 16 * s + j0), packed,
                               __ATOMIC_RELAXED, __HIP_MEMORY_SCOPE_AGENT);
        }

        // after step 0, swap persistent weights W0 -> W_eff (overlaps barrier)
        if (t == 0) {
#pragma unroll
            for (int tt = 0; tt < 3; ++tt) {
                if (tt < ntcount) {
                    const int row = 80 * s + (ntile0 + tt) * 16 + l15;
#pragma unroll
                    for (int kk = 0; kk < 16; ++kk) {
                        bfrag[tt][kk] = *(const half8*)(Wbig + (size_t)row * 512 + kk * 32 + q4 * 8);
                    }
                }
            }
        }

        // ---- group barrier (agent scope, monotone counter) ----
        __syncthreads();  // drains this block's h stores (vmcnt) before arrive
        if (tid == 0) {
            __hip_atomic_fetch_add(cnt, 1u, __ATOMIC_RELEASE, __HIP_MEMORY_SCOPE_AGENT);
            const unsigned int target = 32u * (unsigned)(t + 1);
            while (__hip_atomic_load(cnt, __ATOMIC_RELAXED, __HIP_MEMORY_SCOPE_AGENT) < target) {
            }
        }
        __syncthreads();
        __threadfence();  // acquire: invalidate L1/L2 before next stage reads
    }
}

// ---------------- launch ----------------
extern "C" void kernel_launch(void* const* d_in, const int* in_sizes, int n_in,
                              void* d_out, int out_size, void* d_ws, size_t ws_size,
                              hipStream_t stream) {
    const float* z = (const float*)d_in[0];
    const float* Wih = (const float*)d_in[1];
    const float* Whh = (const float*)d_in[2];
    const float* bih = (const float*)d_in[3];
    const float* bhh = (const float*)d_in[4];
    const float* Wlast = (const float*)d_in[5];
    const float* blast = (const float*)d_in[6];
    float* out = (float*)d_out;

    char* ws = (char*)d_ws;
    unsigned short* Wbig = (unsigned short*)(ws);                // 2560*512*2 = 2,621,440 B
    unsigned short* W0big = (unsigned short*)(ws + 2621440);     // 2,621,440 B
    float* biasEff = (float*)(ws + 5242880);                     // 10,240 B
    float* bias0 = (float*)(ws + 5253120);                       // 10,240 B
    unsigned short* hbuf = (unsigned short*)(ws + 5263360);      // 8*2*32*512*2 = 524,288 B
    unsigned int* counters = (unsigned int*)(ws + 5787648);      // 2,048 B  (total ~5.8 MB)

    k_weff<<<128, 256, 0, stream>>>(Wih, Whh, Wlast, Wbig);
    k_pack<<<512, 256, 0, stream>>>(z, Wih, Whh, bih, bhh, Wlast, blast, Wbig, W0big, biasEff,
                                    bias0, hbuf, counters);
    k_lstm<<<256, 256, 0, stream>>>(Wbig, W0big, biasEff, bias0, hbuf, counters, z, out);
}

// Round 3
// 2237.560 us; speedup vs baseline: 5.0177x; 5.0177x over previous
//
#include <hip/hip_runtime.h>

// VaeRNNDecoder: 512-step LSTM with output feedback, B=256, H=512.
// Folded recurrence: gates_t = h_t @ W_eff^T + b_eff,  W_eff = W_ih@W_last + W_hh.
// 8 groups (XCD-affine) x 32 slice-blocks; weights persistent in VGPR/AGPR as fp16
// MFMA B-fragments; per-step h exchange via LLC (sc0 sc1 accesses, NO fences)
// + relaxed agent-scope counter barrier.

#define HH 512
#define TT 512

typedef _Float16 half8 __attribute__((ext_vector_type(8)));
typedef float f32x4 __attribute__((ext_vector_type(4)));

__device__ __forceinline__ float sigm(float x) { return 1.0f / (1.0f + __expf(-x)); }
__device__ __forceinline__ float tanh_(float x) { return 1.0f - 2.0f / (__expf(2.0f * x) + 1.0f); }
__device__ __forceinline__ unsigned short f16b(float x) {
    _Float16 h = (_Float16)x;
    return __builtin_bit_cast(unsigned short, h);
}

// ---------------- K1: W_eff gate rows -> Wbig (packed, f16) ----------------
__global__ __launch_bounds__(256) void k_weff(const float* __restrict__ Wih,
                                              const float* __restrict__ Whh,
                                              const float* __restrict__ Wlast,
                                              unsigned short* __restrict__ Wbig) {
    __shared__ float wih[16 * 512];
    const int tid = threadIdx.x;
    const int r0 = blockIdx.x * 16;
    for (int i = tid; i < (16 * 512) / 4; i += 256) {
        ((float4*)wih)[i] = ((const float4*)(Wih + (size_t)r0 * 512))[i];
    }
    __syncthreads();
    float acc0[16], acc1[16];
#pragma unroll
    for (int rr = 0; rr < 16; ++rr) { acc0[rr] = 0.f; acc1[rr] = 0.f; }
    const int k0 = tid * 2;
    for (int j = 0; j < 512; ++j) {
        const float2 wl = *(const float2*)(Wlast + (size_t)j * 512 + k0);
#pragma unroll
        for (int rr = 0; rr < 16; ++rr) {
            const float a = wih[rr * 512 + j];
            acc0[rr] += a * wl.x;
            acc1[rr] += a * wl.y;
        }
    }
#pragma unroll
    for (int rr = 0; rr < 16; ++rr) {
        const int gr = r0 + rr;
        const int q = gr >> 9, j = gr & 511;
        const int dst = 80 * (j >> 4) + q * 16 + (j & 15);
        const float v0 = acc0[rr] + Whh[(size_t)gr * 512 + k0];
        const float v1 = acc1[rr] + Whh[(size_t)gr * 512 + k0 + 1];
        Wbig[(size_t)dst * 512 + k0] = f16b(v0);
        Wbig[(size_t)dst * 512 + k0 + 1] = f16b(v1);
    }
}

// ---------------- K2: pack W0big, y-rows, biases, hbuf init, counters ------
__global__ __launch_bounds__(256) void k_pack(const float* __restrict__ z,
                                              const float* __restrict__ Wih,
                                              const float* __restrict__ Whh,
                                              const float* __restrict__ bih,
                                              const float* __restrict__ bhh,
                                              const float* __restrict__ Wlast,
                                              const float* __restrict__ blast,
                                              unsigned short* __restrict__ Wbig,
                                              unsigned short* __restrict__ W0big,
                                              float* __restrict__ biasEff,
                                              float* __restrict__ bias0,
                                              unsigned short* __restrict__ hbuf,
                                              unsigned int* __restrict__ counters) {
    const int nthr = gridDim.x * blockDim.x;
    const int gtid = blockIdx.x * blockDim.x + threadIdx.x;
    for (int e = gtid; e < 2560 * 512; e += nthr) {
        const int r = e >> 9, k = e & 511;
        const int s = r / 80, rem = r - s * 80;
        const int tau = rem >> 4, jj = rem & 15;
        const int j = s * 16 + jj;
        if (tau == 4) {
            const unsigned short v = f16b(Wlast[(size_t)j * 512 + k]);
            Wbig[e] = v;
            W0big[e] = v;
        } else {
            const int gr = tau * 512 + j;
            W0big[e] = f16b(Wih[(size_t)gr * 512 + k] + Whh[(size_t)gr * 512 + k]);
        }
    }
    for (int r = gtid; r < 2560; r += nthr) {
        const int s = r / 80, rem = r - s * 80;
        const int tau = rem >> 4, jj = rem & 15;
        const int j = s * 16 + jj;
        if (tau == 4) {
            bias0[r] = blast[j];
            biasEff[r] = blast[j];
        } else {
            const int gr = tau * 512 + j;
            const float base = bih[gr] + bhh[gr];
            float dot = 0.f;
            for (int k = 0; k < 512; ++k) dot += Wih[(size_t)gr * 512 + k] * blast[k];
            bias0[r] = base;
            biasEff[r] = base + dot;
        }
    }
    for (int e = gtid; e < 256 * 512; e += nthr) {
        const int b = e >> 9, k = e & 511;
        const int g = b >> 5, bl = b & 31;
        hbuf[((size_t)(g * 2) * 32 + bl) * 512 + k] = f16b(z[e]);
    }
    for (int e = gtid; e < 512; e += nthr) counters[e] = 0u;
}

// ---------------- K3: persistent recurrence ----------------
// 256 blocks = 8 groups (blockIdx&7, XCD-affine) x 32 slices (blockIdx>>3).
// Block owns 16 hidden indices: 64 gate rows + 16 y rows of packed Wbig.
// Waves: w0: Mtile0 x {i,f,g}; w1: Mtile0 x {o,y}; w2: Mtile1 x {i,f,g}; w3: Mtile1 x {o,y}.
__global__ __launch_bounds__(256, 1) void k_lstm(const unsigned short* __restrict__ Wbig,
                                                 const unsigned short* __restrict__ W0big,
                                                 const float* __restrict__ biasEff,
                                                 const float* __restrict__ bias0,
                                                 unsigned short* __restrict__ hbuf,
                                                 unsigned int* __restrict__ counters,
                                                 const float* __restrict__ z,
                                                 float* __restrict__ out) {
    const int g = blockIdx.x & 7;
    const int s = blockIdx.x >> 3;
    const int tid = threadIdx.x;
    const int wave = tid >> 6;
    const int lane = tid & 63;
    const int l15 = lane & 15;
    const int q4 = lane >> 4;

    __shared__ unsigned short hstage[32 * 520];  // padded rows: stride 520 halves
    __shared__ float gatesL[32 * 68];            // [b][i(16) f(16) g(16) o(16)], stride 68
    __shared__ float cL[32 * 18];                // cell state, stride 18

    const int mbase = (wave >> 1) * 16;
    const int ntile0 = (wave & 1) ? 3 : 0;
    const int ntcount = (wave & 1) ? 2 : 3;

    unsigned short* hb0 = hbuf + (size_t)(g * 2) * 32 * 512;
    unsigned short* hb1 = hb0 + 32 * 512;
    unsigned int* cnt = counters + g * 64;

    // c init from z (fp32 exact)
    for (int idx = tid; idx < 512; idx += 256) {
        const int b = idx >> 4, jj = idx & 15;
        cL[b * 18 + jj] = z[(size_t)(g * 32 + b) * 512 + 16 * s + jj];
    }

    // persistent B-fragments (fp16 weights), start with W0
    half8 bfrag[3][16];
#pragma unroll
    for (int tt = 0; tt < 3; ++tt) {
        if (tt < ntcount) {
            const int row = 80 * s + (ntile0 + tt) * 16 + l15;
#pragma unroll
            for (int kk = 0; kk < 16; ++kk) {
                bfrag[tt][kk] = *(const half8*)(W0big + (size_t)row * 512 + kk * 32 + q4 * 8);
            }
        }
    }
    float bias0v[3], biasEv[3];
#pragma unroll
    for (int tt = 0; tt < 3; ++tt) {
        if (tt < ntcount) {
            const int r = 80 * s + (ntile0 + tt) * 16 + l15;
            bias0v[tt] = bias0[r];
            biasEv[tt] = biasEff[r];
        } else {
            bias0v[tt] = 0.f;
            biasEv[tt] = 0.f;
        }
    }

    for (int t = 0; t <= 512; ++t) {
        // ---- stage h(t): coherent LLC loads (sc0 sc1), pipelined, one wait ----
        // NOTE: outputs MUST be early-clobber (=&v): loads write dest regs while
        // later loads in the same asm block still need their address pairs.
        {
            const unsigned short* src = (t & 1) ? hb1 : hb0;
            const char* p = (const char*)src + tid * 16;
            half8 st[8];
            asm volatile(
                "global_load_dwordx4 %0, %8, off sc0 sc1\n\t"
                "global_load_dwordx4 %1, %9, off sc0 sc1\n\t"
                "global_load_dwordx4 %2, %10, off sc0 sc1\n\t"
                "global_load_dwordx4 %3, %11, off sc0 sc1\n\t"
                "global_load_dwordx4 %4, %12, off sc0 sc1\n\t"
                "global_load_dwordx4 %5, %13, off sc0 sc1\n\t"
                "global_load_dwordx4 %6, %14, off sc0 sc1\n\t"
                "global_load_dwordx4 %7, %15, off sc0 sc1\n\t"
                "s_waitcnt vmcnt(0)"
                : "=&v"(st[0]), "=&v"(st[1]), "=&v"(st[2]), "=&v"(st[3]),
                  "=&v"(st[4]), "=&v"(st[5]), "=&v"(st[6]), "=&v"(st[7])
                : "v"(p), "v"(p + 4096), "v"(p + 8192), "v"(p + 12288),
                  "v"(p + 16384), "v"(p + 20480), "v"(p + 24576), "v"(p + 28672)
                : "memory");
#pragma unroll
            for (int i = 0; i < 8; ++i) {
                const int ci = i * 256 + tid;  // 16B chunk index, 0..2047
                const int row = ci >> 6, col = ci & 63;
                *(half8*)(hstage + row * 520 + col * 8) = st[i];
            }
        }
        __syncthreads();

        // ---- MFMA: [gates | y] = h @ Wbig_slice^T + bias ----
        f32x4 acc[3];
#pragma unroll
        for (int tt = 0; tt < 3; ++tt) {
            const float bv = (t == 0) ? bias0v[tt] : biasEv[tt];
            acc[tt] = (f32x4){bv, bv, bv, bv};
        }
#pragma unroll
        for (int kk = 0; kk < 16; ++kk) {
            const half8 a = *(const half8*)(hstage + (mbase + l15) * 520 + kk * 32 + q4 * 8);
#pragma unroll
            for (int tt = 0; tt < 3; ++tt) {
                if (tt < ntcount)
                    acc[tt] = __builtin_amdgcn_mfma_f32_16x16x32_f16(a, bfrag[tt][kk], acc[tt], 0, 0, 0);
            }
        }

        // ---- y_{t-1} output (waves 1/3 hold the y tile in acc[1]) ----
        if ((wave & 1) && t >= 1) {
            const int n = 16 * s + l15;
#pragma unroll
            for (int r = 0; r < 4; ++r) {
                const int m = mbase + q4 * 4 + r;
                const size_t off = (size_t)(g * 32 + m) * (TT * HH) + (size_t)(t - 1) * HH + n;
                out[off] = acc[1][r];
            }
        }
        if (t == 512) break;

        // ---- gate tiles -> LDS ----
        {
            const int nst = (wave & 1) ? 1 : 3;
#pragma unroll
            for (int tt = 0; tt < 3; ++tt) {
                if (tt < nst) {
                    const int col = (ntile0 + tt) * 16 + l15;
#pragma unroll
                    for (int r = 0; r < 4; ++r) {
                        const int m = mbase + q4 * 4 + r;
                        gatesL[m * 68 + col] = acc[tt][r];
                    }
                }
            }
        }
        __syncthreads();

        // ---- cell update: 2 cells per thread; publish h(t+1) to LLC ----
        {
            const int b = tid >> 3, jp = tid & 7;
            const int j0 = jp * 2;
            const float2 iv = *(const float2*)(gatesL + b * 68 + j0);
            const float2 fv = *(const float2*)(gatesL + b * 68 + 16 + j0);
            const float2 gv = *(const float2*)(gatesL + b * 68 + 32 + j0);
            const float2 ov = *(const float2*)(gatesL + b * 68 + 48 + j0);
            float2 cv = *(const float2*)(cL + b * 18 + j0);
            const float c0 = sigm(fv.x) * cv.x + sigm(iv.x) * tanh_(gv.x);
            const float c1 = sigm(fv.y) * cv.y + sigm(iv.y) * tanh_(gv.y);
            const float h0 = sigm(ov.x) * tanh_(c0);
            const float h1 = sigm(ov.y) * tanh_(c1);
            cv.x = c0;
            cv.y = c1;
            *(float2*)(cL + b * 18 + j0) = cv;
            unsigned short* dst = (t & 1) ? hb0 : hb1;  // parity (t+1)&1
            const unsigned int packed = (unsigned int)f16b(h0) | ((unsigned int)f16b(h1) << 16);
            __hip_atomic_store((unsigned int*)(dst + b * 512 + 16 * s + j0), packed,
                               __ATOMIC_RELAXED, __HIP_MEMORY_SCOPE_AGENT);
        }

        // after step 0, swap persistent weights W0 -> W_eff (overlaps barrier)
        if (t == 0) {
#pragma unroll
            for (int tt = 0; tt < 3; ++tt) {
                if (tt < ntcount) {
                    const int row = 80 * s + (ntile0 + tt) * 16 + l15;
#pragma unroll
                    for (int kk = 0; kk < 16; ++kk) {
                        bfrag[tt][kk] = *(const half8*)(Wbig + (size_t)row * 512 + kk * 32 + q4 * 8);
                    }
                }
            }
        }

        // ---- group barrier: relaxed agent counter, no fences ----
        // __syncthreads drains every thread's h stores (vmcnt ack at LLC for
        // sc1 stores) before tid0 arrives, so readers polling the counter and
        // then loading with sc0 sc1 observe the new h values.
        __syncthreads();
        if (tid == 0) {
            __hip_atomic_fetch_add(cnt, 1u, __ATOMIC_RELAXED, __HIP_MEMORY_SCOPE_AGENT);
            const unsigned int target = 32u * (unsigned)(t + 1);
            while (__hip_atomic_load(cnt, __ATOMIC_RELAXED, __HIP_MEMORY_SCOPE_AGENT) < target) {
            }
        }
        __syncthreads();
    }
}

// ---------------- launch ----------------
extern "C" void kernel_launch(void* const* d_in, const int* in_sizes, int n_in,
                              void* d_out, int out_size, void* d_ws, size_t ws_size,
                              hipStream_t stream) {
    const float* z = (const float*)d_in[0];
    const float* Wih = (const float*)d_in[1];
    const float* Whh = (const float*)d_in[2];
    const float* bih = (const float*)d_in[3];
    const float* bhh = (const float*)d_in[4];
    const float* Wlast = (const float*)d_in[5];
    const float* blast = (const float*)d_in[6];
    float* out = (float*)d_out;

    char* ws = (char*)d_ws;
    unsigned short* Wbig = (unsigned short*)(ws);                // 2,621,440 B
    unsigned short* W0big = (unsigned short*)(ws + 2621440);     // 2,621,440 B
    float* biasEff = (float*)(ws + 5242880);                     // 10,240 B
    float* bias0 = (float*)(ws + 5253120);                       // 10,240 B
    unsigned short* hbuf = (unsigned short*)(ws + 5263360);      // 524,288 B
    unsigned int* counters = (unsigned int*)(ws + 5787648);      // 2,048 B

    k_weff<<<128, 256, 0, stream>>>(Wih, Whh, Wlast, Wbig);
    k_pack<<<512, 256, 0, stream>>>(z, Wih, Whh, bih, bhh, Wlast, blast, Wbig, W0big, biasEff,
                                    bias0, hbuf, counters);
    k_lstm<<<256, 256, 0, stream>>>(Wbig, W0big, biasEff, bias0, hbuf, counters, z, out);
}